// Round 2
// baseline (198.784 us; speedup 1.0000x reference)
//
#include <hip/hip_runtime.h>

// y[i,j] = (x[i,j] != 0) ? f / (count_i * f) : 0
// count_i = nonzeros in row i. One workgroup per row of 8192 fp32 elements;
// 256 threads x 32 elems/thread (8x float4); mask kept in one 32-bit word per
// thread so x is read exactly once. Row count via xor-butterfly (all lanes
// defined) + LDS partials summed redundantly by every thread (no single-writer
// broadcast, no second barrier).

#define D 8192
#define BLOCK 256

__global__ __launch_bounds__(BLOCK) void filt_norm_kernel(
    const float* __restrict__ x, const float* __restrict__ f,
    float* __restrict__ y) {
    const int row = blockIdx.x;
    const int t   = threadIdx.x;
    const long long base = (long long)row * D;
    const float4* __restrict__ xv = reinterpret_cast<const float4*>(x + base);
    float4* __restrict__ yv       = reinterpret_cast<float4*>(y + base);

    // Coalesced: at step k, the wave's 64 lanes read 1 KiB contiguous.
    float4 v[8];
#pragma unroll
    for (int k = 0; k < 8; ++k) v[k] = xv[k * BLOCK + t];

    unsigned mask = 0u;
#pragma unroll
    for (int k = 0; k < 8; ++k) {
        mask |= (v[k].x != 0.0f ? 1u : 0u) << (4 * k + 0);
        mask |= (v[k].y != 0.0f ? 1u : 0u) << (4 * k + 1);
        mask |= (v[k].z != 0.0f ? 1u : 0u) << (4 * k + 2);
        mask |= (v[k].w != 0.0f ? 1u : 0u) << (4 * k + 3);
    }

    // Wave64 xor-butterfly: every lane ends with the full wave sum (all
    // exchanged values are defined at every step — no out-of-range reads).
    int cnt = __popc(mask);
#pragma unroll
    for (int off = 1; off < 64; off <<= 1) cnt += __shfl_xor(cnt, off, 64);

    // Per-wave partials in LDS; every thread sums all 4 itself.
    __shared__ int wsum[BLOCK / 64];
    const int wid = t >> 6;
    if ((t & 63) == 0) wsum[wid] = cnt;
    __syncthreads();
    const int total = wsum[0] + wsum[1] + wsum[2] + wsum[3];

    // Match reference fp32 arithmetic exactly:
    // denom = float(count) * f; safe = count>0 ? denom : 1; val = f / safe.
    const float fs    = f[0];
    const float denom = (float)total * fs;
    const float safe  = (total > 0) ? denom : 1.0f;
    const float val   = fs / safe;

#pragma unroll
    for (int k = 0; k < 8; ++k) {
        float4 o;
        o.x = ((mask >> (4 * k + 0)) & 1u) ? val : 0.0f;
        o.y = ((mask >> (4 * k + 1)) & 1u) ? val : 0.0f;
        o.z = ((mask >> (4 * k + 2)) & 1u) ? val : 0.0f;
        o.w = ((mask >> (4 * k + 3)) & 1u) ? val : 0.0f;
        yv[k * BLOCK + t] = o;
    }
}

extern "C" void kernel_launch(void* const* d_in, const int* in_sizes, int n_in,
                              void* d_out, int out_size, void* d_ws, size_t ws_size,
                              hipStream_t stream) {
    const float* x = (const float*)d_in[0];
    const float* f = (const float*)d_in[1];
    float* y       = (float*)d_out;
    const int rows = in_sizes[0] / D;  // 16384
    filt_norm_kernel<<<dim3(rows), dim3(BLOCK), 0, stream>>>(x, f, y);
}

// Round 5
// 198.066 us; speedup vs baseline: 1.0036x; 1.0036x over previous
//
#include <hip/hip_runtime.h>

// y[i,j] = (x[i,j] != 0) ? f / (count_i * f) : 0
// count_i = nonzeros in row i. One workgroup per row of 8192 fp32 elements;
// 256 threads x 32 elems/thread (8x float4); mask kept in one 32-bit word per
// thread so x is read exactly once. Row count via xor-butterfly (all lanes
// defined) + LDS partials summed redundantly by every thread (no single-writer
// broadcast, no second barrier).
//
// NOTE: this is byte-for-byte the R2 kernel that PASSED (198.8 us, absmax 0.0).
// R1 (shfl_down variant) and R4 (two-pass variant) both failed the post-timing
// re-validation with absmax ~= 1/min_row_count — the all-unwritten-output
// signature — despite bit-exact eager validation. A/A retest to distinguish
// kernel-dependent from harness/HW-transient failure before optimizing further.

#define D 8192
#define BLOCK 256

__global__ __launch_bounds__(BLOCK) void filt_norm_kernel(
    const float* __restrict__ x, const float* __restrict__ f,
    float* __restrict__ y) {
    const int row = blockIdx.x;
    const int t   = threadIdx.x;
    const long long base = (long long)row * D;
    const float4* __restrict__ xv = reinterpret_cast<const float4*>(x + base);
    float4* __restrict__ yv       = reinterpret_cast<float4*>(y + base);

    // Coalesced: at step k, the wave's 64 lanes read 1 KiB contiguous.
    float4 v[8];
#pragma unroll
    for (int k = 0; k < 8; ++k) v[k] = xv[k * BLOCK + t];

    unsigned mask = 0u;
#pragma unroll
    for (int k = 0; k < 8; ++k) {
        mask |= (v[k].x != 0.0f ? 1u : 0u) << (4 * k + 0);
        mask |= (v[k].y != 0.0f ? 1u : 0u) << (4 * k + 1);
        mask |= (v[k].z != 0.0f ? 1u : 0u) << (4 * k + 2);
        mask |= (v[k].w != 0.0f ? 1u : 0u) << (4 * k + 3);
    }

    // Wave64 xor-butterfly: every lane ends with the full wave sum (all
    // exchanged values are defined at every step — no out-of-range reads).
    int cnt = __popc(mask);
#pragma unroll
    for (int off = 1; off < 64; off <<= 1) cnt += __shfl_xor(cnt, off, 64);

    // Per-wave partials in LDS; every thread sums all 4 itself.
    __shared__ int wsum[BLOCK / 64];
    const int wid = t >> 6;
    if ((t & 63) == 0) wsum[wid] = cnt;
    __syncthreads();
    const int total = wsum[0] + wsum[1] + wsum[2] + wsum[3];

    // Match reference fp32 arithmetic exactly:
    // denom = float(count) * f; safe = count>0 ? denom : 1; val = f / safe.
    const float fs    = f[0];
    const float denom = (float)total * fs;
    const float safe  = (total > 0) ? denom : 1.0f;
    const float val   = fs / safe;

#pragma unroll
    for (int k = 0; k < 8; ++k) {
        float4 o;
        o.x = ((mask >> (4 * k + 0)) & 1u) ? val : 0.0f;
        o.y = ((mask >> (4 * k + 1)) & 1u) ? val : 0.0f;
        o.z = ((mask >> (4 * k + 2)) & 1u) ? val : 0.0f;
        o.w = ((mask >> (4 * k + 3)) & 1u) ? val : 0.0f;
        yv[k * BLOCK + t] = o;
    }
}

extern "C" void kernel_launch(void* const* d_in, const int* in_sizes, int n_in,
                              void* d_out, int out_size, void* d_ws, size_t ws_size,
                              hipStream_t stream) {
    const float* x = (const float*)d_in[0];
    const float* f = (const float*)d_in[1];
    float* y       = (float*)d_out;
    const int rows = in_sizes[0] / D;  // 16384
    filt_norm_kernel<<<dim3(rows), dim3(BLOCK), 0, stream>>>(x, f, y);
}